// Round 2
// baseline (282.063 us; speedup 1.0000x reference)
//
#include <hip/hip_runtime.h>

#define NBLOCKS 2048
#define NTHREADS 256
#define PER_THREAD 16   // float4s per thread on the fast path
#define BATCH 4         // loads kept in flight per wave: 2*BATCH dwordx4

__global__ __launch_bounds__(NTHREADS) void wmse_kernel(
    const float4* __restrict__ pred4,
    const int4* __restrict__ lab4,
    const float* __restrict__ weights,
    float* __restrict__ out,
    int n4, double inv_n)
{
    __shared__ float w[16];
    if (threadIdx.x < 10) w[threadIdx.x] = weights[threadIdx.x];
    __syncthreads();

    const int stride = NBLOCKS * NTHREADS;          // 524288
    const int base = blockIdx.x * NTHREADS + threadIdx.x;

    double acc = 0.0;

    if (n4 == stride * PER_THREAD) {
        // fast path: compile-time trip counts, batched loads for MLP
        #pragma unroll 1
        for (int b = 0; b < PER_THREAD / BATCH; ++b) {
            float4 p[BATCH];
            int4   l[BATCH];
            #pragma unroll
            for (int k = 0; k < BATCH; ++k) {
                int i = base + (b * BATCH + k) * stride;
                p[k] = pred4[i];
                l[k] = lab4[i];
            }
            float s = 0.f;
            #pragma unroll
            for (int k = 0; k < BATCH; ++k) {
                float d0 = p[k].x - (float)l[k].x;
                float d1 = p[k].y - (float)l[k].y;
                float d2 = p[k].z - (float)l[k].z;
                float d3 = p[k].w - (float)l[k].w;
                s += w[l[k].x] * d0 * d0;
                s += w[l[k].y] * d1 * d1;
                s += w[l[k].z] * d2 * d2;
                s += w[l[k].w] * d3 * d3;
            }
            acc += (double)s;   // 16 f32 terms per double add: safe
        }
    } else {
        // generic fallback (not taken for N = 2^25)
        for (int i = base; i < n4; i += stride) {
            float4 p = pred4[i];
            int4 l = lab4[i];
            float d0 = p.x - (float)l.x;
            float d1 = p.y - (float)l.y;
            float d2 = p.z - (float)l.z;
            float d3 = p.w - (float)l.w;
            float s = w[l.x] * d0 * d0
                    + w[l.y] * d1 * d1
                    + w[l.z] * d2 * d2
                    + w[l.w] * d3 * d3;
            acc += (double)s;
        }
    }

    // 64-lane wave shuffle reduction (f64)
    for (int off = 32; off > 0; off >>= 1)
        acc += __shfl_down(acc, off, 64);

    __shared__ double wave_sums[NTHREADS / 64];
    int lane = threadIdx.x & 63;
    int wid  = threadIdx.x >> 6;
    if (lane == 0) wave_sums[wid] = acc;
    __syncthreads();

    if (threadIdx.x == 0) {
        double t = 0.0;
        #pragma unroll
        for (int k = 0; k < NTHREADS / 64; ++k) t += wave_sums[k];
        // one low-contention atomic per block; out was zeroed by memset node
        atomicAdd(out, (float)(t * inv_n));
    }
}

extern "C" void kernel_launch(void* const* d_in, const int* in_sizes, int n_in,
                              void* d_out, int out_size, void* d_ws, size_t ws_size,
                              hipStream_t stream) {
    const float* pred    = (const float*)d_in[0];
    const int*   labels  = (const int*)d_in[1];
    const float* weights = (const float*)d_in[2];
    float* out = (float*)d_out;

    int n  = in_sizes[0];          // 33,554,432 = 2^25
    int n4 = n >> 2;

    // d_out is re-poisoned to 0xAA before every timed launch — zero it here.
    hipMemsetAsync(out, 0, out_size * sizeof(float), stream);

    wmse_kernel<<<NBLOCKS, NTHREADS, 0, stream>>>(
        (const float4*)pred, (const int4*)labels, weights, out,
        n4, 1.0 / (double)n);
}

// Round 3
// 277.249 us; speedup vs baseline: 1.0174x; 1.0174x over previous
//
#include <hip/hip_runtime.h>

#define NBLOCKS 2048
#define NTHREADS 256
#define PER_THREAD 16   // float4 groups per thread (fast path): 2048*256*16*4 = 2^25

__global__ __launch_bounds__(NTHREADS) void wmse_kernel(
    const float4* __restrict__ pred4,
    const int4* __restrict__ lab4,
    const float* __restrict__ weights,
    float* __restrict__ out,
    int n4, double inv_n)
{
    __shared__ float w[16];
    if (threadIdx.x < 10) w[threadIdx.x] = weights[threadIdx.x];
    __syncthreads();

    const int stride = NBLOCKS * NTHREADS;          // 524288 float4s
    const int base = blockIdx.x * NTHREADS + threadIdx.x;

    double acc = 0.0;

    if (n4 == stride * PER_THREAD) {
        // -------- software-pipelined fast path --------
        // current pair of groups (registers)
        float4 pa, pb; int4 la, lb;
        // prefetched next pair
        float4 pc, pd; int4 lc, ld;

        // prologue: issue stage-0 loads
        la = lab4 [base + 0 * stride];
        pa = pred4[base + 0 * stride];
        lb = lab4 [base + 1 * stride];
        pb = pred4[base + 1 * stride];

        #pragma unroll
        for (int s = 0; s < 8; ++s) {
            if (s < 7) {
                // issue next stage's 4 loads BEFORE consuming current stage
                lc = lab4 [base + (2 * s + 2) * stride];
                pc = pred4[base + (2 * s + 2) * stride];
                ld = lab4 [base + (2 * s + 3) * stride];
                pd = pred4[base + (2 * s + 3) * stride];
            }

            // consume current stage: two independent f32 chains
            float d0 = pa.x - (float)la.x;
            float d1 = pa.y - (float)la.y;
            float d2 = pa.z - (float)la.z;
            float d3 = pa.w - (float)la.w;
            float sA = w[la.x] * d0 * d0 + w[la.y] * d1 * d1
                     + w[la.z] * d2 * d2 + w[la.w] * d3 * d3;

            float e0 = pb.x - (float)lb.x;
            float e1 = pb.y - (float)lb.y;
            float e2 = pb.z - (float)lb.z;
            float e3 = pb.w - (float)lb.w;
            float sB = w[lb.x] * e0 * e0 + w[lb.y] * e1 * e1
                     + w[lb.z] * e2 * e2 + w[lb.w] * e3 * e3;

            acc += (double)(sA + sB);

            // rotate (fully unrolled -> pure register renaming)
            pa = pc; la = lc; pb = pd; lb = ld;
        }
    } else {
        // generic fallback (not taken for N = 2^25)
        for (int i = base; i < n4; i += stride) {
            float4 p = pred4[i];
            int4 l = lab4[i];
            float d0 = p.x - (float)l.x;
            float d1 = p.y - (float)l.y;
            float d2 = p.z - (float)l.z;
            float d3 = p.w - (float)l.w;
            acc += (double)(w[l.x] * d0 * d0 + w[l.y] * d1 * d1
                          + w[l.z] * d2 * d2 + w[l.w] * d3 * d3);
        }
    }

    // 64-lane wave shuffle reduction (f64)
    for (int off = 32; off > 0; off >>= 1)
        acc += __shfl_down(acc, off, 64);

    __shared__ double wave_sums[NTHREADS / 64];
    int lane = threadIdx.x & 63;
    int wid  = threadIdx.x >> 6;
    if (lane == 0) wave_sums[wid] = acc;
    __syncthreads();

    if (threadIdx.x == 0) {
        double t = 0.0;
        #pragma unroll
        for (int k = 0; k < NTHREADS / 64; ++k) t += wave_sums[k];
        atomicAdd(out, (float)(t * inv_n));   // out zeroed by memset node
    }
}

extern "C" void kernel_launch(void* const* d_in, const int* in_sizes, int n_in,
                              void* d_out, int out_size, void* d_ws, size_t ws_size,
                              hipStream_t stream) {
    const float* pred    = (const float*)d_in[0];
    const int*   labels  = (const int*)d_in[1];
    const float* weights = (const float*)d_in[2];
    float* out = (float*)d_out;

    int n  = in_sizes[0];          // 33,554,432 = 2^25
    int n4 = n >> 2;

    hipMemsetAsync(out, 0, out_size * sizeof(float), stream);

    wmse_kernel<<<NBLOCKS, NTHREADS, 0, stream>>>(
        (const float4*)pred, (const int4*)labels, weights, out,
        n4, 1.0 / (double)n);
}

// Round 5
// 261.262 us; speedup vs baseline: 1.0796x; 1.0612x over previous
//
#include <hip/hip_runtime.h>

#define NBLOCKS 8192
#define NTHREADS 256
// 8192 blocks * 256 threads = 2,097,152 threads; each handles 4 float4 groups
// -> 2^23 float4 = 2^25 elements exactly.

typedef float fvec4 __attribute__((ext_vector_type(4)));
typedef int   ivec4 __attribute__((ext_vector_type(4)));

__device__ __forceinline__ fvec4 ntloadf(const fvec4* p) {
    return __builtin_nontemporal_load(p);
}
__device__ __forceinline__ ivec4 ntloadi(const ivec4* p) {
    return __builtin_nontemporal_load(p);
}

__global__ __launch_bounds__(NTHREADS) void wmse_kernel(
    const fvec4* __restrict__ pred4,
    const ivec4* __restrict__ lab4,
    const float* __restrict__ weights,
    double* __restrict__ partials,
    int n4)
{
    __shared__ float w[16];
    if (threadIdx.x < 10) w[threadIdx.x] = weights[threadIdx.x];
    __syncthreads();

    const int stride = NBLOCKS * NTHREADS;       // 2,097,152 float4 groups
    const int t = blockIdx.x * NTHREADS + threadIdx.x;

    double acc = 0.0;

    if (n4 == stride * 4) {
        // ---- flat fast path: 8 fully independent nontemporal loads ----
        fvec4 p0 = ntloadf(pred4 + t);
        fvec4 p1 = ntloadf(pred4 + t + stride);
        fvec4 p2 = ntloadf(pred4 + t + 2 * stride);
        fvec4 p3 = ntloadf(pred4 + t + 3 * stride);
        ivec4 l0 = ntloadi(lab4 + t);
        ivec4 l1 = ntloadi(lab4 + t + stride);
        ivec4 l2 = ntloadi(lab4 + t + 2 * stride);
        ivec4 l3 = ntloadi(lab4 + t + 3 * stride);

        float s0, s1, s2, s3;
        {
            float d0 = p0.x - (float)l0.x, d1 = p0.y - (float)l0.y;
            float d2 = p0.z - (float)l0.z, d3 = p0.w - (float)l0.w;
            s0 = w[l0.x]*d0*d0 + w[l0.y]*d1*d1 + w[l0.z]*d2*d2 + w[l0.w]*d3*d3;
        }
        {
            float d0 = p1.x - (float)l1.x, d1 = p1.y - (float)l1.y;
            float d2 = p1.z - (float)l1.z, d3 = p1.w - (float)l1.w;
            s1 = w[l1.x]*d0*d0 + w[l1.y]*d1*d1 + w[l1.z]*d2*d2 + w[l1.w]*d3*d3;
        }
        {
            float d0 = p2.x - (float)l2.x, d1 = p2.y - (float)l2.y;
            float d2 = p2.z - (float)l2.z, d3 = p2.w - (float)l2.w;
            s2 = w[l2.x]*d0*d0 + w[l2.y]*d1*d1 + w[l2.z]*d2*d2 + w[l2.w]*d3*d3;
        }
        {
            float d0 = p3.x - (float)l3.x, d1 = p3.y - (float)l3.y;
            float d2 = p3.z - (float)l3.z, d3 = p3.w - (float)l3.w;
            s3 = w[l3.x]*d0*d0 + w[l3.y]*d1*d1 + w[l3.z]*d2*d2 + w[l3.w]*d3*d3;
        }
        acc = (double)((s0 + s1) + (s2 + s3));
    } else {
        // generic fallback (not taken for N = 2^25)
        for (int i = t; i < n4; i += stride) {
            fvec4 p = pred4[i];
            ivec4 l = lab4[i];
            float d0 = p.x - (float)l.x, d1 = p.y - (float)l.y;
            float d2 = p.z - (float)l.z, d3 = p.w - (float)l.w;
            acc += (double)(w[l.x]*d0*d0 + w[l.y]*d1*d1
                          + w[l.z]*d2*d2 + w[l.w]*d3*d3);
        }
    }

    // 64-lane wave shuffle reduction (f64)
    for (int off = 32; off > 0; off >>= 1)
        acc += __shfl_down(acc, off, 64);

    __shared__ double wave_sums[NTHREADS / 64];
    int lane = threadIdx.x & 63;
    int wid  = threadIdx.x >> 6;
    if (lane == 0) wave_sums[wid] = acc;
    __syncthreads();

    if (threadIdx.x == 0) {
        double tsum = 0.0;
        #pragma unroll
        for (int k = 0; k < NTHREADS / 64; ++k) tsum += wave_sums[k];
        partials[blockIdx.x] = tsum;
    }
}

__global__ __launch_bounds__(NTHREADS) void wmse_final_kernel(
    const double* __restrict__ partials,
    float* __restrict__ out,
    int nparts,
    double inv_n)
{
    double acc = 0.0;
    for (int i = threadIdx.x; i < nparts; i += NTHREADS)
        acc += partials[i];

    for (int off = 32; off > 0; off >>= 1)
        acc += __shfl_down(acc, off, 64);

    __shared__ double wave_sums[NTHREADS / 64];
    int lane = threadIdx.x & 63;
    int wid  = threadIdx.x >> 6;
    if (lane == 0) wave_sums[wid] = acc;
    __syncthreads();

    if (threadIdx.x == 0) {
        double t = 0.0;
        #pragma unroll
        for (int k = 0; k < NTHREADS / 64; ++k) t += wave_sums[k];
        out[0] = (float)(t * inv_n);
    }
}

extern "C" void kernel_launch(void* const* d_in, const int* in_sizes, int n_in,
                              void* d_out, int out_size, void* d_ws, size_t ws_size,
                              hipStream_t stream) {
    const float* pred    = (const float*)d_in[0];
    const int*   labels  = (const int*)d_in[1];
    const float* weights = (const float*)d_in[2];
    float* out = (float*)d_out;

    int n  = in_sizes[0];          // 33,554,432 = 2^25
    int n4 = n >> 2;

    double* partials = (double*)d_ws;   // 8192 doubles = 64 KB

    wmse_kernel<<<NBLOCKS, NTHREADS, 0, stream>>>(
        (const fvec4*)pred, (const ivec4*)labels, weights, partials, n4);

    wmse_final_kernel<<<1, NTHREADS, 0, stream>>>(
        partials, out, NBLOCKS, 1.0 / (double)n);
}